// Round 1
// baseline (2634.601 us; speedup 1.0000x reference)
//
#include <hip/hip_runtime.h>
#include <math.h>

#define Bsz 32
#define Hd  1024
#define Sd  512
#define Vd  32000

__device__ __forceinline__ float sigf(float x){ return 1.0f/(1.0f+expf(-x)); }

// x[b][k] = embedding[ids[b]][k]
__global__ void k_embed(const int* __restrict__ ids, const float* __restrict__ emb,
                        float* __restrict__ x){
  int t = blockIdx.x*256 + threadIdx.x;          // B*H threads
  int b = t >> 10, k = t & (Hd-1);
  x[t] = emb[(size_t)ids[b]*Hd + k];
}

// One GRU cell: h' = (1-z)*n + z*h  (torch gate order r,z,n)
// thread t: b = t&31 (lane-minor so W loads are wave-broadcast), j = t>>5
__global__ void k_gru(const float* __restrict__ x, const float* __restrict__ h,
                      const float* __restrict__ Wih, const float* __restrict__ Whh,
                      const float* __restrict__ bih, const float* __restrict__ bhh,
                      float* __restrict__ hnew){
  int t = blockIdx.x*256 + threadIdx.x;
  int b = t & (Bsz-1);
  int j = t >> 5;
  const float4* x4  = (const float4*)(x + (size_t)b*Hd);
  const float4* h4  = (const float4*)(h + (size_t)b*Hd);
  const float4* wir = (const float4*)(Wih + (size_t)j*Hd);
  const float4* wiz = (const float4*)(Wih + (size_t)(Hd+j)*Hd);
  const float4* win = (const float4*)(Wih + (size_t)(2*Hd+j)*Hd);
  const float4* whr = (const float4*)(Whh + (size_t)j*Hd);
  const float4* whz = (const float4*)(Whh + (size_t)(Hd+j)*Hd);
  const float4* whn = (const float4*)(Whh + (size_t)(2*Hd+j)*Hd);
  float air=0.f,aiz=0.f,ain=0.f,ahr=0.f,ahz=0.f,ahn=0.f;
  for (int k=0;k<Hd/4;k++){
    float4 xv=x4[k], hv=h4[k], w;
    w=wir[k]; air += xv.x*w.x+xv.y*w.y+xv.z*w.z+xv.w*w.w;
    w=wiz[k]; aiz += xv.x*w.x+xv.y*w.y+xv.z*w.z+xv.w*w.w;
    w=win[k]; ain += xv.x*w.x+xv.y*w.y+xv.z*w.z+xv.w*w.w;
    w=whr[k]; ahr += hv.x*w.x+hv.y*w.y+hv.z*w.z+hv.w*w.w;
    w=whz[k]; ahz += hv.x*w.x+hv.y*w.y+hv.z*w.z+hv.w*w.w;
    w=whn[k]; ahn += hv.x*w.x+hv.y*w.y+hv.z*w.z+hv.w*w.w;
  }
  float r = sigf(air + bih[j]      + ahr + bhh[j]);
  float z = sigf(aiz + bih[Hd+j]   + ahz + bhh[Hd+j]);
  float n = tanhf(ain + bih[2*Hd+j] + r*(ahn + bhh[2*Hd+j]));
  hnew[(size_t)b*Hd + j] = (1.f-z)*n + z*h[(size_t)b*Hd + j];
}

// sp[b][j] = fc1_b[j] + h0[b]·fc1_w[j, 0:H] + h1[b]·fc1_w[j, H:2H]
__global__ void k_stateproj(const float* __restrict__ h0, const float* __restrict__ h1,
                            const float* __restrict__ fc1w, const float* __restrict__ fc1b,
                            float* __restrict__ sp){
  int t = blockIdx.x*256 + threadIdx.x;
  int b = t & (Bsz-1);
  int j = t >> 5;
  const float4* a0 = (const float4*)(h0 + (size_t)b*Hd);
  const float4* a1 = (const float4*)(h1 + (size_t)b*Hd);
  const float4* w0 = (const float4*)(fc1w + (size_t)j*3*Hd);
  const float4* w1 = w0 + Hd/4;
  float acc = fc1b[j];
  for (int k=0;k<Hd/4;k++){
    float4 av=a0[k], wv=w0[k];
    acc += av.x*wv.x+av.y*wv.y+av.z*wv.z+av.w*wv.w;
    av=a1[k]; wv=w1[k];
    acc += av.x*wv.x+av.y*wv.y+av.z*wv.z+av.w*wv.w;
  }
  sp[(size_t)b*Hd + j] = acc;
}

// Fused: proj[r][j] = enc_row[r]·fc1_w[j, 2H:3H]; then
// e[r] += sum_j fc2w[j]*tanh(proj + sp[b][j]);  r = s*B + b, b = r&31
// 64x64 tile GEMM (K=1024, BK=16), 16x16 threads, 4x4 microtile.
__global__ void k_att_gemm(const float* __restrict__ enc, const float* __restrict__ fc1w,
                           const float* __restrict__ sp, const float* __restrict__ fc2w,
                           float* __restrict__ e){
  __shared__ __align__(16) float As[16][64];
  __shared__ __align__(16) float Bs[16][64];
  __shared__ float red[16][65];
  const int tid  = threadIdx.x;
  const int row0 = blockIdx.y * 64;   // over S*B = 16384
  const int col0 = blockIdx.x * 64;   // over H = 1024
  const int tm = tid >> 4, tn = tid & 15;
  const int i4 = tid * 4;
  const int lm = i4 >> 4;             // 0..63 (load row)
  const int lk = i4 & 15;             // 0,4,8,12
  const float* ga = enc  + (size_t)(row0+lm)*Hd + lk;
  const float* gb = fc1w + (size_t)(col0+lm)*3*Hd + 2*Hd + lk;
  float acc[4][4] = {};
  for (int k0=0;k0<Hd;k0+=16){
    float4 a  = *(const float4*)(ga + k0);
    float4 bv = *(const float4*)(gb + k0);
    As[lk+0][lm]=a.x;  As[lk+1][lm]=a.y;  As[lk+2][lm]=a.z;  As[lk+3][lm]=a.w;
    Bs[lk+0][lm]=bv.x; Bs[lk+1][lm]=bv.y; Bs[lk+2][lm]=bv.z; Bs[lk+3][lm]=bv.w;
    __syncthreads();
    for (int k=0;k<16;k++){
      float4 av = *(const float4*)&As[k][tm*4];
      float4 bw = *(const float4*)&Bs[k][tn*4];
      acc[0][0]+=av.x*bw.x; acc[0][1]+=av.x*bw.y; acc[0][2]+=av.x*bw.z; acc[0][3]+=av.x*bw.w;
      acc[1][0]+=av.y*bw.x; acc[1][1]+=av.y*bw.y; acc[1][2]+=av.y*bw.z; acc[1][3]+=av.y*bw.w;
      acc[2][0]+=av.z*bw.x; acc[2][1]+=av.z*bw.y; acc[2][2]+=av.z*bw.z; acc[2][3]+=av.z*bw.w;
      acc[3][0]+=av.w*bw.x; acc[3][1]+=av.w*bw.y; acc[3][2]+=av.w*bw.z; acc[3][3]+=av.w*bw.w;
    }
    __syncthreads();
  }
  float part[4];
  for (int i=0;i<4;i++){
    int row = row0 + tm*4 + i;
    int b   = row & (Bsz-1);
    float p = 0.f;
    for (int j=0;j<4;j++){
      int col = col0 + tn*4 + j;
      p += fc2w[col] * tanhf(acc[i][j] + sp[(size_t)b*Hd + col]);
    }
    part[i] = p;
  }
  for (int i=0;i<4;i++) red[tn][tm*4+i] = part[i];
  __syncthreads();
  if (tid < 64){
    float s = 0.f;
    for (int q=0;q<16;q++) s += red[q][tid];
    atomicAdd(&e[row0 + tid], s);
  }
}

// In-place softmax over s for each b. e indexed [s*B + b]. One block per b.
__global__ void k_softmax(float* __restrict__ e){
  const int b = blockIdx.x, t = threadIdx.x;
  __shared__ float red[256];
  float v1 = e[t*Bsz + b], v2 = e[(t+256)*Bsz + b];
  red[t] = fmaxf(v1, v2);
  __syncthreads();
  for (int off=128; off; off>>=1){ if (t<off) red[t]=fmaxf(red[t],red[t+off]); __syncthreads(); }
  float m = red[0];
  __syncthreads();
  float e1 = expf(v1-m), e2 = expf(v2-m);
  red[t] = e1 + e2;
  __syncthreads();
  for (int off=128; off; off>>=1){ if (t<off) red[t]+=red[t+off]; __syncthreads(); }
  float inv = 1.0f/red[0];
  e[t*Bsz + b] = e1*inv;
  e[(t+256)*Bsz + b] = e2*inv;
}

// ctx[b][h] += sum_{s in chunk} alpha[s*B+b]*enc[s][b][h]; grid (B, 8 s-chunks)
__global__ void k_context(const float* __restrict__ alpha, const float* __restrict__ enc,
                          float* __restrict__ ctx){
  const int b = blockIdx.x, c = blockIdx.y, t = threadIdx.x;
  float4 acc = {0,0,0,0};
  for (int s = c*64; s < c*64 + 64; s++){
    float a = alpha[s*Bsz + b];
    float4 ev = *(const float4*)(enc + (size_t)(s*Bsz+b)*Hd + t*4);
    acc.x += a*ev.x; acc.y += a*ev.y; acc.z += a*ev.z; acc.w += a*ev.w;
  }
  float* p = ctx + (size_t)b*Hd + t*4;
  atomicAdd(p+0, acc.x); atomicAdd(p+1, acc.y);
  atomicAdd(p+2, acc.z); atomicAdd(p+3, acc.w);
}

// out1[b][j] = relu(bias[j] + [h1,ctx,ctxp][b]·W[j,:])
__global__ void k_attnfc(const float* __restrict__ h1, const float* __restrict__ ctx,
                         const float* __restrict__ ctxp, const float* __restrict__ W,
                         const float* __restrict__ bias, float* __restrict__ out1){
  int t = blockIdx.x*256 + threadIdx.x;
  int b = t & (Bsz-1);
  int j = t >> 5;
  const float4* a0 = (const float4*)(h1   + (size_t)b*Hd);
  const float4* a1 = (const float4*)(ctx  + (size_t)b*Hd);
  const float4* a2 = (const float4*)(ctxp + (size_t)b*Hd);
  const float4* w0 = (const float4*)(W + (size_t)j*3*Hd);
  const float4* w1 = w0 + Hd/4;
  const float4* w2 = w0 + Hd/2;
  float acc = bias[j];
  for (int k=0;k<Hd/4;k++){
    float4 av,wv;
    av=a0[k]; wv=w0[k]; acc += av.x*wv.x+av.y*wv.y+av.z*wv.z+av.w*wv.w;
    av=a1[k]; wv=w1[k]; acc += av.x*wv.x+av.y*wv.y+av.z*wv.z+av.w*wv.w;
    av=a2[k]; wv=w2[k]; acc += av.x*wv.x+av.y*wv.y+av.z*wv.z+av.w*wv.w;
  }
  out1[(size_t)b*Hd + j] = fmaxf(acc, 0.f);
}

// logits[b][v] = out1[b]·fc_w[v] + fc_b[v]
__global__ void k_logits(const float* __restrict__ out1, const float* __restrict__ fcw,
                         const float* __restrict__ fcb, float* __restrict__ lg){
  int t = blockIdx.x*256 + threadIdx.x;   // B*V threads
  int b = t & (Bsz-1);
  int v = t >> 5;
  const float4* a = (const float4*)(out1 + (size_t)b*Hd);
  const float4* w = (const float4*)(fcw + (size_t)v*Hd);
  float acc = 0.f;
  for (int k=0;k<Hd/4;k++){
    float4 av=a[k], wv=w[k];
    acc += av.x*wv.x+av.y*wv.y+av.z*wv.z+av.w*wv.w;
  }
  lg[(size_t)b*Vd + v] = acc + fcb[v];
}

extern "C" void kernel_launch(void* const* d_in, const int* in_sizes, int n_in,
                              void* d_out, int out_size, void* d_ws, size_t ws_size,
                              hipStream_t stream) {
  const int*   ids  = (const int*)  d_in[0];
  const float* hid  = (const float*)d_in[1];
  const float* enc  = (const float*)d_in[2];
  const float* encp = (const float*)d_in[3];
  const float* emb  = (const float*)d_in[4];
  const float* Wih0 = (const float*)d_in[5];
  const float* Whh0 = (const float*)d_in[6];
  const float* bih0 = (const float*)d_in[7];
  const float* bhh0 = (const float*)d_in[8];
  const float* Wih1 = (const float*)d_in[9];
  const float* Whh1 = (const float*)d_in[10];
  const float* bih1 = (const float*)d_in[11];
  const float* bhh1 = (const float*)d_in[12];
  const float* afc1w= (const float*)d_in[13];
  const float* afc1b= (const float*)d_in[14];
  const float* afc2w= (const float*)d_in[15];
  /* d_in[16] att_fc2_b: scalar shift, softmax-invariant -> unused */
  const float* pfc1w= (const float*)d_in[17];
  const float* pfc1b= (const float*)d_in[18];
  const float* pfc2w= (const float*)d_in[19];
  /* d_in[20] attp_fc2_b unused */
  const float* nfcw = (const float*)d_in[21];
  const float* nfcb = (const float*)d_in[22];
  const float* fcw  = (const float*)d_in[23];
  const float* fcb  = (const float*)d_in[24];

  float* outp   = (float*)d_out;
  float* logits = outp;                          // [B,V]
  float* h0     = outp + (size_t)Bsz*Vd;         // new_hidden[0] [B,H]
  float* h1     = h0 + Bsz*Hd;                   // new_hidden[1] [B,H]

  float* ws   = (float*)d_ws;                    // < 1 MB total scratch
  float* x    = ws;                              // 32768
  float* spa  = ws +  32768;                     // 32768
  float* spp  = ws +  65536;                     // 32768
  float* ea   = ws +  98304;                     // 16384  (energy -> alpha, [s*B+b])
  float* ep   = ws + 114688;                     // 16384
  float* ctx  = ws + 131072;                     // 32768
  float* ctxp = ws + 163840;                     // 32768
  float* o1   = ws + 196608;                     // 32768

  // zero e + ctx buffers (they are accumulated via atomics): contiguous region
  hipMemsetAsync(ea, 0, (size_t)(2*Sd*Bsz + 2*Bsz*Hd)*sizeof(float), stream);

  k_embed    <<<Bsz*Hd/256, 256, 0, stream>>>(ids, emb, x);
  k_gru      <<<Bsz*Hd/256, 256, 0, stream>>>(x,  hid,          Wih0, Whh0, bih0, bhh0, h0);
  k_gru      <<<Bsz*Hd/256, 256, 0, stream>>>(h0, hid + Bsz*Hd, Wih1, Whh1, bih1, bhh1, h1);
  k_stateproj<<<Bsz*Hd/256, 256, 0, stream>>>(h0, h1, afc1w, afc1b, spa);
  k_stateproj<<<Bsz*Hd/256, 256, 0, stream>>>(h0, h1, pfc1w, pfc1b, spp);

  dim3 g(Hd/64, Sd*Bsz/64);
  k_att_gemm<<<g, 256, 0, stream>>>(enc,  afc1w, spa, afc2w, ea);
  k_att_gemm<<<g, 256, 0, stream>>>(encp, pfc1w, spp, pfc2w, ep);

  k_softmax<<<Bsz, 256, 0, stream>>>(ea);
  k_softmax<<<Bsz, 256, 0, stream>>>(ep);

  dim3 gc(Bsz, 8);
  k_context<<<gc, 256, 0, stream>>>(ea, enc,  ctx);
  k_context<<<gc, 256, 0, stream>>>(ep, encp, ctxp);

  k_attnfc<<<Bsz*Hd/256, 256, 0, stream>>>(h1, ctx, ctxp, nfcw, nfcb, o1);
  k_logits<<<Bsz*Vd/256, 256, 0, stream>>>(o1, fcw, fcb, logits);
}

// Round 2
// 1164.444 us; speedup vs baseline: 2.2625x; 2.2625x over previous
//
#include <hip/hip_runtime.h>
#include <math.h>

#define Bsz 32
#define Hd  1024
#define Sd  512
#define Vd  32000

typedef __attribute__((ext_vector_type(8))) short v8s;
typedef __attribute__((ext_vector_type(4))) float v4f;

__device__ __forceinline__ float sigf(float x){ return 1.0f/(1.0f+__expf(-x)); }
__device__ __forceinline__ float ftanh(float x){
  float e = __expf(2.0f*x);
  return 1.0f - 2.0f/(e+1.0f);
}
// pack two fp32 -> two bf16 (truncate) in one v_perm_b32
__device__ __forceinline__ unsigned pk(float lo, float hi){
  return __builtin_amdgcn_perm(__float_as_uint(hi), __float_as_uint(lo), 0x07060302u);
}

// x[b][k] = embedding[ids[b]][k]
__global__ void k_embed(const int* __restrict__ ids, const float* __restrict__ emb,
                        float* __restrict__ x){
  int t = blockIdx.x*256 + threadIdx.x;          // B*H threads
  int b = t >> 10, k = t & (Hd-1);
  x[t] = emb[(size_t)ids[b]*Hd + k];
}

// gbuf[g][j][b] = (g<3 ? x : h)[b] . W[g%3 row j]   (g = 0..5; r,z,n x2)
__global__ void k_gru_gates(const float* __restrict__ x, const float* __restrict__ h,
                            const float* __restrict__ Wih, const float* __restrict__ Whh,
                            float* __restrict__ gbuf){
  int t = blockIdx.x*256 + threadIdx.x;   // 6*B*H threads
  int b = t & (Bsz-1);
  int j = (t >> 5) & (Hd-1);
  int g = t >> 15;
  const float* vec = (g < 3) ? (x + (size_t)b*Hd) : (h + (size_t)b*Hd);
  const float* wr  = (g < 3) ? (Wih + (size_t)(g*Hd + j)*Hd)
                             : (Whh + (size_t)((g-3)*Hd + j)*Hd);
  const float4* v4 = (const float4*)vec;
  const float4* w4 = (const float4*)wr;
  float acc = 0.f;
  for (int k=0;k<Hd/4;k++){
    float4 a=v4[k], w=w4[k];
    acc += a.x*w.x+a.y*w.y+a.z*w.z+a.w*w.w;
  }
  gbuf[(size_t)g*Bsz*Hd + (size_t)j*Bsz + b] = acc;
}

__global__ void k_gru_combine(const float* __restrict__ gbuf, const float* __restrict__ h,
                              const float* __restrict__ bih, const float* __restrict__ bhh,
                              float* __restrict__ hnew){
  int t = blockIdx.x*256 + threadIdx.x;  // B*H threads
  int b = t & (Bsz-1), j = t >> 5;
  const float* gb = gbuf + (size_t)j*Bsz + b;
  float ir = gb[0*32768], iz = gb[1*32768], in_ = gb[2*32768];
  float hr = gb[3*32768], hz = gb[4*32768], hn = gb[5*32768];
  float r = sigf(ir + bih[j]      + hr + bhh[j]);
  float z = sigf(iz + bih[Hd+j]   + hz + bhh[Hd+j]);
  float n = ftanh(in_ + bih[2*Hd+j] + r*(hn + bhh[2*Hd+j]));
  hnew[(size_t)b*Hd + j] = (1.f-z)*n + z*h[(size_t)b*Hd + j];
}

// sp[b][j] = fc1_b[j] + h0[b].fc1_w[j, 0:H] + h1[b].fc1_w[j, H:2H]
__global__ void k_stateproj(const float* __restrict__ h0, const float* __restrict__ h1,
                            const float* __restrict__ fc1w, const float* __restrict__ fc1b,
                            float* __restrict__ sp){
  int t = blockIdx.x*256 + threadIdx.x;
  int b = t & (Bsz-1);
  int j = t >> 5;
  const float4* a0 = (const float4*)(h0 + (size_t)b*Hd);
  const float4* a1 = (const float4*)(h1 + (size_t)b*Hd);
  const float4* w0 = (const float4*)(fc1w + (size_t)j*3*Hd);
  const float4* w1 = w0 + Hd/4;
  float acc = fc1b[j];
  for (int k=0;k<Hd/4;k++){
    float4 av=a0[k], wv=w0[k];
    acc += av.x*wv.x+av.y*wv.y+av.z*wv.z+av.w*wv.w;
    av=a1[k]; wv=w1[k];
    acc += av.x*wv.x+av.y*wv.y+av.z*wv.z+av.w*wv.w;
  }
  sp[(size_t)b*Hd + j] = acc;
}

// MFMA attention GEMM, fused epilogue.
// C[r][c] = enc_row[r] . fc1w[c, 2H:3H]  (r over S*B=16384, c over H=1024)
// e[r] += sum_c fc2w[c]*tanh(C[r][c] + sp[r&31][c])
// 128x128 tile, BK=64, 4 waves (2x2), 16x16x32 bf16 MFMA, in-register f32->bf16.
__global__ __launch_bounds__(256, 2)
void k_att_mfma(const float* __restrict__ enc, const float* __restrict__ fc1w,
                const float* __restrict__ sp, const float* __restrict__ fc2w,
                float* __restrict__ e){
  __shared__ __align__(16) ushort As[128*64];   // [row][k] bf16
  __shared__ __align__(16) ushort Bs[128*64];   // [col][k] bf16
  const int t = threadIdx.x;
  const int lane = t & 63;
  const int w = t >> 6;
  const int wm = w >> 1, wn = w & 1;
  const int q = lane >> 4, c15 = lane & 15;
  const int row0 = blockIdx.y * 128;   // over S*B
  const int col0 = blockIdx.x * 128;   // over H

  // staging assignment: chunk c = t + i*256 -> row c>>3, k-part (c&7)*8
  const int lrow = t >> 3;             // 0..31
  const int lkp  = (t & 7) * 8;        // 0,8,..,56
  const float* gA = enc  + (size_t)(row0 + lrow)*Hd + lkp;
  const float* gB = fc1w + (size_t)(col0 + lrow)*3*Hd + 2*Hd + lkp;
  uint* wA = (uint*)&As[t*8];
  uint* wB = (uint*)&Bs[t*8];

  v4f acc[4][4];
  for (int mi=0;mi<4;mi++) for (int ni=0;ni<4;ni++) acc[mi][ni] = (v4f){0.f,0.f,0.f,0.f};

  for (int k0 = 0; k0 < Hd; k0 += 64){
    #pragma unroll
    for (int i = 0; i < 4; i++){
      float4 a0 = *(const float4*)(gA + (size_t)i*32*Hd + k0);
      float4 a1 = *(const float4*)(gA + (size_t)i*32*Hd + k0 + 4);
      float4 b0 = *(const float4*)(gB + (size_t)i*32*3*Hd + k0);
      float4 b1 = *(const float4*)(gB + (size_t)i*32*3*Hd + k0 + 4);
      uint4 pa = { pk(a0.x,a0.y), pk(a0.z,a0.w), pk(a1.x,a1.y), pk(a1.z,a1.w) };
      uint4 pb = { pk(b0.x,b0.y), pk(b0.z,b0.w), pk(b1.x,b1.y), pk(b1.z,b1.w) };
      *(uint4*)(wA + i*1024) = pa;
      *(uint4*)(wB + i*1024) = pb;
    }
    __syncthreads();
    #pragma unroll
    for (int kk = 0; kk < 2; kk++){
      v8s af[4], bf[4];
      #pragma unroll
      for (int mi=0;mi<4;mi++)
        af[mi] = *(const v8s*)&As[(wm*64 + mi*16 + c15)*64 + kk*32 + q*8];
      #pragma unroll
      for (int ni=0;ni<4;ni++)
        bf[ni] = *(const v8s*)&Bs[(wn*64 + ni*16 + c15)*64 + kk*32 + q*8];
      #pragma unroll
      for (int mi=0;mi<4;mi++)
        #pragma unroll
        for (int ni=0;ni<4;ni++)
          acc[mi][ni] = __builtin_amdgcn_mfma_f32_16x16x32_bf16(af[mi], bf[ni], acc[mi][ni], 0, 0, 0);
    }
    __syncthreads();
  }

  // epilogue: per-row partial of fc2 . tanh(C + sp)
  #pragma unroll
  for (int mi=0;mi<4;mi++){
    float rs[4] = {0.f,0.f,0.f,0.f};
    #pragma unroll
    for (int ni=0;ni<4;ni++){
      int col = col0 + wn*64 + ni*16 + c15;
      float w2 = fc2w[col];
      int bb = (mi & 1) * 16;
      #pragma unroll
      for (int r=0;r<4;r++){
        int b = bb + q*4 + r;     // global row & 31
        float xv = acc[mi][ni][r] + sp[(size_t)b*Hd + col];
        rs[r] += w2 * ftanh(xv);
      }
    }
    #pragma unroll
    for (int r=0;r<4;r++){
      float v = rs[r];
      v += __shfl_xor(v, 1);
      v += __shfl_xor(v, 2);
      v += __shfl_xor(v, 4);
      v += __shfl_xor(v, 8);
      if (c15 == 0)
        atomicAdd(&e[row0 + wm*64 + mi*16 + q*4 + r], v);
    }
  }
}

// In-place softmax over s for each b. e indexed [s*B + b]. One block per b.
__global__ void k_softmax(float* __restrict__ e){
  const int b = blockIdx.x, t = threadIdx.x;
  __shared__ float red[256];
  float v1 = e[t*Bsz + b], v2 = e[(t+256)*Bsz + b];
  red[t] = fmaxf(v1, v2);
  __syncthreads();
  for (int off=128; off; off>>=1){ if (t<off) red[t]=fmaxf(red[t],red[t+off]); __syncthreads(); }
  float m = red[0];
  __syncthreads();
  float e1 = expf(v1-m), e2 = expf(v2-m);
  red[t] = e1 + e2;
  __syncthreads();
  for (int off=128; off; off>>=1){ if (t<off) red[t]+=red[t+off]; __syncthreads(); }
  float inv = 1.0f/red[0];
  e[t*Bsz + b] = e1*inv;
  e[(t+256)*Bsz + b] = e2*inv;
}

// ctx[b][h] += sum_{s in chunk} alpha[s*B+b]*enc[s][b][h]; grid (B, 8 s-chunks)
__global__ void k_context(const float* __restrict__ alpha, const float* __restrict__ enc,
                          float* __restrict__ ctx){
  const int b = blockIdx.x, c = blockIdx.y, t = threadIdx.x;
  float4 acc = {0,0,0,0};
  for (int s = c*64; s < c*64 + 64; s++){
    float a = alpha[s*Bsz + b];
    float4 ev = *(const float4*)(enc + (size_t)(s*Bsz+b)*Hd + t*4);
    acc.x += a*ev.x; acc.y += a*ev.y; acc.z += a*ev.z; acc.w += a*ev.w;
  }
  float* p = ctx + (size_t)b*Hd + t*4;
  atomicAdd(p+0, acc.x); atomicAdd(p+1, acc.y);
  atomicAdd(p+2, acc.z); atomicAdd(p+3, acc.w);
}

// out1[b][j] = relu(bias[j] + [h1,ctx,ctxp][b].W[j,:])
__global__ void k_attnfc(const float* __restrict__ h1, const float* __restrict__ ctx,
                         const float* __restrict__ ctxp, const float* __restrict__ W,
                         const float* __restrict__ bias, float* __restrict__ out1){
  int t = blockIdx.x*256 + threadIdx.x;
  int b = t & (Bsz-1);
  int j = t >> 5;
  const float4* a0 = (const float4*)(h1   + (size_t)b*Hd);
  const float4* a1 = (const float4*)(ctx  + (size_t)b*Hd);
  const float4* a2 = (const float4*)(ctxp + (size_t)b*Hd);
  const float4* w0 = (const float4*)(W + (size_t)j*3*Hd);
  const float4* w1 = w0 + Hd/4;
  const float4* w2 = w0 + Hd/2;
  float acc = bias[j];
  for (int k=0;k<Hd/4;k++){
    float4 av,wv;
    av=a0[k]; wv=w0[k]; acc += av.x*wv.x+av.y*wv.y+av.z*wv.z+av.w*wv.w;
    av=a1[k]; wv=w1[k]; acc += av.x*wv.x+av.y*wv.y+av.z*wv.z+av.w*wv.w;
    av=a2[k]; wv=w2[k]; acc += av.x*wv.x+av.y*wv.y+av.z*wv.z+av.w*wv.w;
  }
  out1[(size_t)b*Hd + j] = fmaxf(acc, 0.f);
}

// logits = out1 @ fcw^T + fcb : M=32, N=32000, K=1024. Tiled LDS GEMM, BN=64, BK=32.
__global__ void k_logits(const float* __restrict__ out1, const float* __restrict__ fcw,
                         const float* __restrict__ fcb, float* __restrict__ lg){
  __shared__ float As[32][36];   // [k][m]
  __shared__ float Bs[32][66];   // [k][n]
  const int t = threadIdx.x;
  const int v0 = blockIdx.x * 64;
  const int tm = t >> 5, tn = t & 31;     // tm: 4 rows each, tn: 2 cols each
  const int alr = t >> 3, alk = t & 7;    // A loader: row, 4-elem k chunk
  const int bvr = t >> 2, bkq = t & 3;    // B loader: v-row, 8-elem k chunk
  const float* pa = out1 + (size_t)alr*Hd + alk*4;
  const float* pb = fcw + (size_t)(v0+bvr)*Hd + bkq*8;
  float acc[4][2] = {};
  for (int k0=0;k0<Hd;k0+=32){
    float4 av = *(const float4*)(pa + k0);
    float4 b0 = *(const float4*)(pb + k0);
    float4 b1 = *(const float4*)(pb + k0 + 4);
    As[alk*4+0][alr]=av.x; As[alk*4+1][alr]=av.y; As[alk*4+2][alr]=av.z; As[alk*4+3][alr]=av.w;
    Bs[bkq*8+0][bvr]=b0.x; Bs[bkq*8+1][bvr]=b0.y; Bs[bkq*8+2][bvr]=b0.z; Bs[bkq*8+3][bvr]=b0.w;
    Bs[bkq*8+4][bvr]=b1.x; Bs[bkq*8+5][bvr]=b1.y; Bs[bkq*8+6][bvr]=b1.z; Bs[bkq*8+7][bvr]=b1.w;
    __syncthreads();
    #pragma unroll
    for (int k=0;k<32;k++){
      float4 a = *(const float4*)&As[k][tm*4];
      float2 b = *(const float2*)&Bs[k][tn*2];
      acc[0][0]+=a.x*b.x; acc[0][1]+=a.x*b.y;
      acc[1][0]+=a.y*b.x; acc[1][1]+=a.y*b.y;
      acc[2][0]+=a.z*b.x; acc[2][1]+=a.z*b.y;
      acc[3][0]+=a.w*b.x; acc[3][1]+=a.w*b.y;
    }
    __syncthreads();
  }
  float2 bias = *(const float2*)&fcb[v0 + tn*2];
  #pragma unroll
  for (int i=0;i<4;i++){
    float2 o = { acc[i][0] + bias.x, acc[i][1] + bias.y };
    *(float2*)&lg[(size_t)(tm*4+i)*Vd + v0 + tn*2] = o;
  }
}

extern "C" void kernel_launch(void* const* d_in, const int* in_sizes, int n_in,
                              void* d_out, int out_size, void* d_ws, size_t ws_size,
                              hipStream_t stream) {
  const int*   ids  = (const int*)  d_in[0];
  const float* hid  = (const float*)d_in[1];
  const float* enc  = (const float*)d_in[2];
  const float* encp = (const float*)d_in[3];
  const float* emb  = (const float*)d_in[4];
  const float* Wih0 = (const float*)d_in[5];
  const float* Whh0 = (const float*)d_in[6];
  const float* bih0 = (const float*)d_in[7];
  const float* bhh0 = (const float*)d_in[8];
  const float* Wih1 = (const float*)d_in[9];
  const float* Whh1 = (const float*)d_in[10];
  const float* bih1 = (const float*)d_in[11];
  const float* bhh1 = (const float*)d_in[12];
  const float* afc1w= (const float*)d_in[13];
  const float* afc1b= (const float*)d_in[14];
  const float* afc2w= (const float*)d_in[15];
  /* d_in[16] att_fc2_b: softmax-invariant -> unused */
  const float* pfc1w= (const float*)d_in[17];
  const float* pfc1b= (const float*)d_in[18];
  const float* pfc2w= (const float*)d_in[19];
  /* d_in[20] attp_fc2_b unused */
  const float* nfcw = (const float*)d_in[21];
  const float* nfcb = (const float*)d_in[22];
  const float* fcw  = (const float*)d_in[23];
  const float* fcb  = (const float*)d_in[24];

  float* outp   = (float*)d_out;
  float* logits = outp;                          // [B,V]
  float* h0     = outp + (size_t)Bsz*Vd;         // new_hidden[0] [B,H]
  float* h1     = h0 + Bsz*Hd;                   // new_hidden[1] [B,H]

  float* ws   = (float*)d_ws;
  float* x    = ws;                              // 32768
  float* spa  = ws +  32768;                     // 32768
  float* spp  = ws +  65536;                     // 32768
  float* ea   = ws +  98304;                     // 16384  (energy -> alpha, [s*B+b])
  float* ep   = ws + 114688;                     // 16384
  float* ctx  = ws + 131072;                     // 32768
  float* ctxp = ws + 163840;                     // 32768
  float* o1   = ws + 196608;                     // 32768
  float* gbuf = ws + 229376;                     // 196608 (6*B*H gate partials)

  // zero atomic-accumulated region: ea, ep, ctx, ctxp (contiguous)
  hipMemsetAsync(ea, 0, (size_t)(2*Sd*Bsz + 2*Bsz*Hd)*sizeof(float), stream);

  k_embed      <<<Bsz*Hd/256, 256, 0, stream>>>(ids, emb, x);
  k_gru_gates  <<<6*Bsz*Hd/256, 256, 0, stream>>>(x, hid, Wih0, Whh0, gbuf);
  k_gru_combine<<<Bsz*Hd/256, 256, 0, stream>>>(gbuf, hid, bih0, bhh0, h0);
  k_gru_gates  <<<6*Bsz*Hd/256, 256, 0, stream>>>(h0, hid + Bsz*Hd, Wih1, Whh1, gbuf);
  k_gru_combine<<<Bsz*Hd/256, 256, 0, stream>>>(gbuf, hid + Bsz*Hd, bih1, bhh1, h1);
  k_stateproj  <<<Bsz*Hd/256, 256, 0, stream>>>(h0, h1, afc1w, afc1b, spa);
  k_stateproj  <<<Bsz*Hd/256, 256, 0, stream>>>(h0, h1, pfc1w, pfc1b, spp);

  dim3 g(Hd/128, Sd*Bsz/128);   // (8, 128)
  k_att_mfma<<<g, 256, 0, stream>>>(enc,  afc1w, spa, afc2w, ea);
  k_att_mfma<<<g, 256, 0, stream>>>(encp, pfc1w, spp, pfc2w, ep);

  k_softmax<<<Bsz, 256, 0, stream>>>(ea);
  k_softmax<<<Bsz, 256, 0, stream>>>(ep);

  dim3 gc(Bsz, 8);
  k_context<<<gc, 256, 0, stream>>>(ea, enc,  ctx);
  k_context<<<gc, 256, 0, stream>>>(ep, encp, ctxp);

  k_attnfc<<<Bsz*Hd/256, 256, 0, stream>>>(h1, ctx, ctxp, nfcw, nfcb, o1);
  k_logits<<<Vd/64, 256, 0, stream>>>(o1, fcw, fcb, logits);
}

// Round 3
// 915.663 us; speedup vs baseline: 2.8773x; 1.2717x over previous
//
#include <hip/hip_runtime.h>
#include <math.h>

#define Bsz 32
#define Hd  1024
#define Sd  512
#define Vd  32000

typedef __attribute__((ext_vector_type(8))) short v8s;
typedef __attribute__((ext_vector_type(4))) float v4f;

__device__ __forceinline__ float sigf(float x){ return 1.0f/(1.0f+__expf(-x)); }
__device__ __forceinline__ float ftanh(float x){
  float e = __expf(2.0f*x);
  return 1.0f - 2.0f/(e+1.0f);
}
// pack two fp32 -> two bf16 (truncate) in one v_perm_b32 (lo in low half)
__device__ __forceinline__ unsigned pk(float lo, float hi){
  return __builtin_amdgcn_perm(__float_as_uint(hi), __float_as_uint(lo), 0x07060302u);
}

// ---- convert fc1w[:, 2H:3H] slices (att + pinyin) to bf16 [j][k] ----
__global__ void k_cvt_fc1w(const float* __restrict__ aw, const float* __restrict__ pw,
                           ushort* __restrict__ ab, ushort* __restrict__ pb){
  int tt = blockIdx.x*256 + threadIdx.x;   // 262144 threads
  int idx = tt*8;
  int s = idx >> 20;                        // 0:a 1:p (1048576 elems each)
  int r = idx & 1048575;
  int j = r >> 10, k = r & 1023;
  const float* src = (s? pw : aw) + (size_t)j*3072 + 2048 + k;
  float4 f0 = *(const float4*)src, f1 = *(const float4*)(src+4);
  uint4 p = { pk(f0.x,f0.y), pk(f0.z,f0.w), pk(f1.x,f1.y), pk(f1.z,f1.w) };
  *(uint4*)((s? pb : ab) + r) = p;
}

// x[b][k] = embedding[ids[b]][k]
__global__ void k_embed(const int* __restrict__ ids, const float* __restrict__ emb,
                        float* __restrict__ x){
  int t = blockIdx.x*256 + threadIdx.x;
  int b = t >> 10, k = t & (Hd-1);
  x[t] = emb[(size_t)ids[b]*Hd + k];
}

// 9 gate-sets x split-4 K: g 0-2: x@Wih0, 3-5: hid0@Whh0, 6-8: hid1@Whh1
__global__ void k_gates9(const float* __restrict__ x, const float* __restrict__ hid,
                         const float* __restrict__ Wih0, const float* __restrict__ Whh0,
                         const float* __restrict__ Whh1, float* __restrict__ gA){
  int blk = blockIdx.x;                 // 9*4*128 = 4608
  int g  = blk >> 9;
  int kc = (blk >> 7) & 3;
  int tt = (blk & 127)*256 + threadIdx.x;
  int b = tt & 31, j = tt >> 5;
  const float* vec; const float* w;
  if (g < 3){ vec = x + b*Hd; w = Wih0 + ((size_t)(g*Hd + j))*Hd; }
  else if (g < 6){ vec = hid + b*Hd; w = Whh0 + ((size_t)((g-3)*Hd + j))*Hd; }
  else { vec = hid + Bsz*Hd + b*Hd; w = Whh1 + ((size_t)((g-6)*Hd + j))*Hd; }
  const float4* v4 = (const float4*)(vec + kc*256);
  const float4* w4 = (const float4*)(w + kc*256);
  float acc = 0.f;
  #pragma unroll 8
  for (int k=0;k<64;k++){ float4 a=v4[k], ww=w4[k];
    acc += a.x*ww.x+a.y*ww.y+a.z*ww.z+a.w*ww.w; }
  atomicAdd(&gA[(size_t)g*32768 + j*32 + b], acc);
}

// 3 gate-sets x split-4 K: h0 @ Wih1
__global__ void k_gates3(const float* __restrict__ h0, const float* __restrict__ Wih1,
                         float* __restrict__ gB){
  int blk = blockIdx.x;                 // 3*4*128 = 1536
  int g  = blk >> 9;
  int kc = (blk >> 7) & 3;
  int tt = (blk & 127)*256 + threadIdx.x;
  int b = tt & 31, j = tt >> 5;
  const float4* v4 = (const float4*)(h0 + b*Hd + kc*256);
  const float4* w4 = (const float4*)(Wih1 + ((size_t)(g*Hd + j))*Hd + kc*256);
  float acc = 0.f;
  #pragma unroll 8
  for (int k=0;k<64;k++){ float4 a=v4[k], ww=w4[k];
    acc += a.x*ww.x+a.y*ww.y+a.z*ww.z+a.w*ww.w; }
  atomicAdd(&gB[(size_t)g*32768 + j*32 + b], acc);
}

// combine gates: xg/hg each 3 sets of [j*32+b] sums; h' per torch GRU
__global__ void k_gru_comb(const float* __restrict__ xg, const float* __restrict__ hg,
                           const float* __restrict__ h, const float* __restrict__ bih,
                           const float* __restrict__ bhh, float* __restrict__ hnew){
  int tt = blockIdx.x*256 + threadIdx.x;
  int b = tt & 31, j = tt >> 5;
  float ir = xg[tt], iz = xg[32768 + tt], in_ = xg[2*32768 + tt];
  float hr = hg[tt], hz = hg[32768 + tt], hn  = hg[2*32768 + tt];
  float r = sigf(ir + bih[j]      + hr + bhh[j]);
  float z = sigf(iz + bih[Hd+j]   + hz + bhh[Hd+j]);
  float n = ftanh(in_ + bih[2*Hd+j] + r*(hn + bhh[2*Hd+j]));
  hnew[(size_t)b*Hd + j] = (1.f-z)*n + z*h[(size_t)b*Hd + j];
}

// state projection split: sp[s][b][j] += [h0|h1] . fc1w[j, 0:2H] chunks (no bias)
__global__ void k_spsplit(const float* __restrict__ h0, const float* __restrict__ h1,
                          const float* __restrict__ afc1w, const float* __restrict__ pfc1w,
                          float* __restrict__ spa_, float* __restrict__ spp_){
  int blk = blockIdx.x;                 // 2*4*128 = 1024
  int s  = blk >> 9;
  int kc = (blk >> 7) & 3;
  int tt = (blk & 127)*256 + threadIdx.x;
  int b = tt & 31, j = tt >> 5;
  const float* w = (s? pfc1w : afc1w) + (size_t)j*3*Hd + kc*512;
  const float* vec = (kc < 2 ? h0 : h1) + b*Hd + (kc & 1)*512;
  const float4* v4 = (const float4*)vec;
  const float4* w4 = (const float4*)w;
  float acc = 0.f;
  #pragma unroll 8
  for (int k=0;k<128;k++){ float4 a=v4[k], ww=w4[k];
    acc += a.x*ww.x+a.y*ww.y+a.z*ww.z+a.w*ww.w; }
  atomicAdd((s? spp_ : spa_) + (size_t)b*Hd + j, acc);
}

// fused MFMA attention GEMM + tanh/fc2/row-reduce epilogue. z: att / pinyin.
__global__ __launch_bounds__(256, 2)
void k_att_mfma(const float* __restrict__ enc0, const float* __restrict__ enc1,
                const ushort* __restrict__ wb0, const ushort* __restrict__ wb1,
                const float* __restrict__ sp0, const float* __restrict__ sp1,
                const float* __restrict__ b10, const float* __restrict__ b11,
                const float* __restrict__ w20, const float* __restrict__ w21,
                float* __restrict__ e0, float* __restrict__ e1){
  const int z = blockIdx.z;
  const float*  enc = z? enc1 : enc0;
  const ushort* wb  = z? wb1  : wb0;
  const float*  sp  = z? sp1  : sp0;
  const float*  b1  = z? b11  : b10;
  const float*  fc2 = z? w21  : w20;
  float* e = z? e1 : e0;
  __shared__ __align__(16) ushort As[128*72];   // [row][k], pad 72 (2-way banks)
  __shared__ __align__(16) ushort Bs[128*72];
  const int t = threadIdx.x;
  const int lane = t & 63;
  const int w = t >> 6;
  const int wm = w >> 1, wn = w & 1;
  const int q = lane >> 4, c15 = lane & 15;
  const int row0 = blockIdx.y * 128;   // over S*B
  const int col0 = blockIdx.x * 128;   // over H

  const int lrow = t >> 3, lkp = (t & 7)*8;     // A staging: 32 rows x 8 kparts
  const float* gA = enc + (size_t)(row0 + lrow)*Hd + lkp;
  const int brow = t >> 1, bkp = (t & 1)*32;    // B staging: 128 rows x 2 halves
  const ushort* gB = wb + (size_t)(col0 + brow)*Hd + bkp;

  v4f acc[4][4];
  for (int mi=0;mi<4;mi++) for (int ni=0;ni<4;ni++) acc[mi][ni] = (v4f){0.f,0.f,0.f,0.f};

  for (int k0 = 0; k0 < Hd; k0 += 64){
    #pragma unroll
    for (int i = 0; i < 4; i++){
      const float* p = gA + (size_t)i*32*Hd + k0;
      float4 a0 = *(const float4*)p;
      float4 a1 = *(const float4*)(p+4);
      uint4 pa = { pk(a0.x,a0.y), pk(a0.z,a0.w), pk(a1.x,a1.y), pk(a1.z,a1.w) };
      *(uint4*)&As[(i*32 + lrow)*72 + lkp] = pa;
    }
    {
      const uint4* pb4 = (const uint4*)(gB + k0);
      uint4 b0_=pb4[0], b1_=pb4[1], b2_=pb4[2], b3_=pb4[3];
      uint4* d = (uint4*)&Bs[brow*72 + bkp];
      d[0]=b0_; d[1]=b1_; d[2]=b2_; d[3]=b3_;
    }
    __syncthreads();
    #pragma unroll
    for (int kk = 0; kk < 2; kk++){
      v8s af[4], bf[4];
      #pragma unroll
      for (int mi=0;mi<4;mi++)
        af[mi] = *(const v8s*)&As[(wm*64 + mi*16 + c15)*72 + kk*32 + q*8];
      #pragma unroll
      for (int ni=0;ni<4;ni++)
        bf[ni] = *(const v8s*)&Bs[(wn*64 + ni*16 + c15)*72 + kk*32 + q*8];
      #pragma unroll
      for (int mi=0;mi<4;mi++)
        #pragma unroll
        for (int ni=0;ni<4;ni++)
          acc[mi][ni] = __builtin_amdgcn_mfma_f32_16x16x32_bf16(af[mi], bf[ni], acc[mi][ni], 0, 0, 0);
    }
    __syncthreads();
  }

  // epilogue: e[row] += sum_col fc2[col]*tanh(C + sp[b][col] + fc1b[col])
  #pragma unroll
  for (int mi=0;mi<4;mi++){
    float rs[4] = {0.f,0.f,0.f,0.f};
    #pragma unroll
    for (int ni=0;ni<4;ni++){
      int col = col0 + wn*64 + ni*16 + c15;
      float w2 = fc2[col];
      float bb1 = b1[col];
      int bb = (mi & 1) * 16;
      #pragma unroll
      for (int r=0;r<4;r++){
        int b = bb + q*4 + r;     // global row & 31
        float xv = acc[mi][ni][r] + sp[(size_t)b*Hd + col] + bb1;
        rs[r] += w2 * ftanh(xv);
      }
    }
    #pragma unroll
    for (int r=0;r<4;r++){
      float v = rs[r];
      v += __shfl_xor(v, 1);
      v += __shfl_xor(v, 2);
      v += __shfl_xor(v, 4);
      v += __shfl_xor(v, 8);
      if (c15 == 0)
        atomicAdd(&e[row0 + wm*64 + mi*16 + q*4 + r], v);
    }
  }
}

// in-place softmax over s per b; y-dim selects att/pinyin
__global__ void k_softmax(float* __restrict__ ea_, float* __restrict__ ep_){
  float* e = blockIdx.y ? ep_ : ea_;
  const int b = blockIdx.x, t = threadIdx.x;
  __shared__ float red[256];
  float v1 = e[t*Bsz + b], v2 = e[(t+256)*Bsz + b];
  red[t] = fmaxf(v1, v2);
  __syncthreads();
  for (int off=128; off; off>>=1){ if (t<off) red[t]=fmaxf(red[t],red[t+off]); __syncthreads(); }
  float m = red[0];
  __syncthreads();
  float e1 = __expf(v1-m), e2 = __expf(v2-m);
  red[t] = e1 + e2;
  __syncthreads();
  for (int off=128; off; off>>=1){ if (t<off) red[t]+=red[t+off]; __syncthreads(); }
  float inv = 1.0f/red[0];
  e[t*Bsz + b] = e1*inv;
  e[(t+256)*Bsz + b] = e2*inv;
}

// ctx[b][h] += sum_s alpha[s*B+b]*enc[s][b][h]; grid (B, 8 s-chunks, 2)
__global__ void k_context(const float* __restrict__ ea_, const float* __restrict__ ep_,
                          const float* __restrict__ enc0, const float* __restrict__ enc1,
                          float* __restrict__ ctx0, float* __restrict__ ctx1){
  const int z = blockIdx.z;
  const float* alpha = z? ep_ : ea_;
  const float* enc   = z? enc1 : enc0;
  float* ctx         = z? ctx1 : ctx0;
  const int b = blockIdx.x, c = blockIdx.y, t = threadIdx.x;
  float4 acc = {0,0,0,0};
  for (int s = c*64; s < c*64 + 64; s++){
    float a = alpha[s*Bsz + b];
    float4 ev = *(const float4*)(enc + (size_t)(s*Bsz+b)*Hd + t*4);
    acc.x += a*ev.x; acc.y += a*ev.y; acc.z += a*ev.z; acc.w += a*ev.w;
  }
  float* p = ctx + (size_t)b*Hd + t*4;
  atomicAdd(p+0, acc.x); atomicAdd(p+1, acc.y);
  atomicAdd(p+2, acc.z); atomicAdd(p+3, acc.w);
}

// attnfc split-K (12 chunks of 256 over [h1|ctx|ctxp]) -> o1acc[j*32+b]
__global__ void k_fcsplit(const float* __restrict__ h1, const float* __restrict__ ctx,
                          const float* __restrict__ ctxp, const float* __restrict__ W,
                          float* __restrict__ o1acc){
  int blk = blockIdx.x;                 // 12*128 = 1536
  int c = blk >> 7;
  int tt = (blk & 127)*256 + threadIdx.x;
  int b = tt & 31, j = tt >> 5;
  int seg = c >> 2, off = (c & 3)*256;
  const float* vec = (seg==0 ? h1 : (seg==1 ? ctx : ctxp)) + b*Hd + off;
  const float* w = W + (size_t)j*3*Hd + seg*Hd + off;
  const float4* v4 = (const float4*)vec;
  const float4* w4 = (const float4*)w;
  float acc = 0.f;
  #pragma unroll 8
  for (int k=0;k<64;k++){ float4 a=v4[k], ww=w4[k];
    acc += a.x*ww.x+a.y*ww.y+a.z*ww.z+a.w*ww.w; }
  atomicAdd(&o1acc[(size_t)j*32 + b], acc);
}

// o1b[b][j] = bf16(relu(o1acc + bias))
__global__ void k_o1comb(const float* __restrict__ o1acc, const float* __restrict__ bias,
                         ushort* __restrict__ o1b){
  int tt = blockIdx.x*256 + threadIdx.x;
  int b = tt & 31, j = tt >> 5;
  float acc = fmaxf(o1acc[tt] + bias[j], 0.f);
  o1b[(size_t)b*Hd + j] = (ushort)(__float_as_uint(acc) >> 16);
}

// logits = o1 @ fcw^T + fcb via streaming bf16 MFMA. 250 blocks x 512 thr, BN=128.
__global__ __launch_bounds__(512)
void k_logits(const ushort* __restrict__ o1b, const float* __restrict__ fcw,
              const float* __restrict__ fcb, float* __restrict__ lg){
  __shared__ __align__(16) ushort Bs[128*72];
  const int t = threadIdx.x;
  const int lane = t & 63, w = t >> 6;   // 8 waves, wave w -> 16 cols
  const int q = lane >> 4, c15 = lane & 15;
  const int v0 = blockIdx.x * 128;
  const int scol = t >> 2, skq = (t & 3) * 16;
  const float* gB = fcw + (size_t)(v0 + scol)*Hd + skq;
  v4f acc[2] = {(v4f){0,0,0,0},(v4f){0,0,0,0}};
  for (int k0=0;k0<Hd;k0+=64){
    float4 f0 = *(const float4*)(gB + k0);
    float4 f1 = *(const float4*)(gB + k0 + 4);
    float4 f2 = *(const float4*)(gB + k0 + 8);
    float4 f3 = *(const float4*)(gB + k0 + 12);
    uint4 p0 = { pk(f0.x,f0.y), pk(f0.z,f0.w), pk(f1.x,f1.y), pk(f1.z,f1.w) };
    uint4 p1 = { pk(f2.x,f2.y), pk(f2.z,f2.w), pk(f3.x,f3.y), pk(f3.z,f3.w) };
    *(uint4*)&Bs[scol*72 + skq] = p0;
    *(uint4*)&Bs[scol*72 + skq + 8] = p1;
    __syncthreads();
    #pragma unroll
    for (int kk=0;kk<2;kk++){
      v8s bfrag = *(const v8s*)&Bs[(w*16 + c15)*72 + kk*32 + q*8];
      #pragma unroll
      for (int mf=0; mf<2; mf++){
        v8s afrag = *(const v8s*)(o1b + (size_t)(mf*16 + c15)*Hd + k0 + kk*32 + q*8);
        acc[mf] = __builtin_amdgcn_mfma_f32_16x16x32_bf16(afrag, bfrag, acc[mf], 0, 0, 0);
      }
    }
    __syncthreads();
  }
  int col = v0 + w*16 + c15;
  float bias = fcb[col];
  #pragma unroll
  for (int mf=0;mf<2;mf++)
    #pragma unroll
    for (int r=0;r<4;r++){
      int b = mf*16 + q*4 + r;
      lg[(size_t)b*Vd + col] = acc[mf][r] + bias;
    }
}

extern "C" void kernel_launch(void* const* d_in, const int* in_sizes, int n_in,
                              void* d_out, int out_size, void* d_ws, size_t ws_size,
                              hipStream_t stream) {
  const int*   ids  = (const int*)  d_in[0];
  const float* hid  = (const float*)d_in[1];
  const float* enc  = (const float*)d_in[2];
  const float* encp = (const float*)d_in[3];
  const float* emb  = (const float*)d_in[4];
  const float* Wih0 = (const float*)d_in[5];
  const float* Whh0 = (const float*)d_in[6];
  const float* bih0 = (const float*)d_in[7];
  const float* bhh0 = (const float*)d_in[8];
  const float* Wih1 = (const float*)d_in[9];
  const float* Whh1 = (const float*)d_in[10];
  const float* bih1 = (const float*)d_in[11];
  const float* bhh1 = (const float*)d_in[12];
  const float* afc1w= (const float*)d_in[13];
  const float* afc1b= (const float*)d_in[14];
  const float* afc2w= (const float*)d_in[15];
  /* d_in[16] att_fc2_b: softmax-invariant -> unused */
  const float* pfc1w= (const float*)d_in[17];
  const float* pfc1b= (const float*)d_in[18];
  const float* pfc2w= (const float*)d_in[19];
  /* d_in[20] attp_fc2_b unused */
  const float* nfcw = (const float*)d_in[21];
  const float* nfcb = (const float*)d_in[22];
  const float* fcw  = (const float*)d_in[23];
  const float* fcb  = (const float*)d_in[24];

  float* outp   = (float*)d_out;
  float* logits = outp;                          // [B,V]
  float* h0     = outp + (size_t)Bsz*Vd;         // new_hidden[0]
  float* h1     = h0 + Bsz*Hd;                   // new_hidden[1]

  float* ws = (float*)d_ws;
  ushort* fc1wab = (ushort*)ws;                       // 1048576 ushorts
  ushort* fc1wpb = (ushort*)(ws + 524288);
  float* x    = ws + 1048576;                         // 32768
  float* spa  = ws + 1081344;                         // 32768  (zeroed)
  float* spp  = ws + 1114112;                         // 32768  (zeroed)
  float* ea   = ws + 1146880;                         // 16384  (zeroed)
  float* ep   = ws + 1163264;                         // 16384  (zeroed)
  float* ctx  = ws + 1179648;                         // 32768  (zeroed)
  float* ctxp = ws + 1212416;                         // 32768  (zeroed)
  float* gA   = ws + 1245184;                         // 294912 (zeroed)
  float* gB   = ws + 1540096;                         // 98304  (zeroed)
  float* o1a  = ws + 1638400;                         // 32768  (zeroed)
  ushort* o1b = (ushort*)(ws + 1671168);              // 32768 ushorts

  // zero all atomic-accumulated buffers: spa..o1a contiguous
  hipMemsetAsync(spa, 0, (size_t)589824*sizeof(float), stream);

  k_cvt_fc1w<<<1024, 256, 0, stream>>>(afc1w, pfc1w, fc1wab, fc1wpb);
  k_embed   <<<Bsz*Hd/256, 256, 0, stream>>>(ids, emb, x);
  k_gates9  <<<4608, 256, 0, stream>>>(x, hid, Wih0, Whh0, Whh1, gA);
  k_gru_comb<<<128, 256, 0, stream>>>(gA, gA + 3*32768, hid, bih0, bhh0, h0);
  k_gates3  <<<1536, 256, 0, stream>>>(h0, Wih1, gB);
  k_gru_comb<<<128, 256, 0, stream>>>(gB, gA + 6*32768, hid + Bsz*Hd, bih1, bhh1, h1);
  k_spsplit <<<1024, 256, 0, stream>>>(h0, h1, afc1w, pfc1w, spa, spp);

  dim3 ga(Hd/128, Sd*Bsz/128, 2);   // (8, 128, 2)
  k_att_mfma<<<ga, 256, 0, stream>>>(enc, encp, fc1wab, fc1wpb, spa, spp,
                                     afc1b, pfc1b, afc2w, pfc2w, ea, ep);

  k_softmax<<<dim3(Bsz,2), 256, 0, stream>>>(ea, ep);
  k_context<<<dim3(Bsz,8,2), 256, 0, stream>>>(ea, ep, enc, encp, ctx, ctxp);

  k_fcsplit<<<1536, 256, 0, stream>>>(h1, ctx, ctxp, nfcw, o1a);
  k_o1comb <<<128, 256, 0, stream>>>(o1a, nfcb, o1b);
  k_logits <<<Vd/128, 512, 0, stream>>>(o1b, fcw, fcb, logits);
}